// Round 16
// baseline (84.287 us; speedup 1.0000x reference)
//
#include <hip/hip_runtime.h>

#define BTOT 65536
#define TST  28
#define PACK_DW 100
// ws layout (dwords): [0 .. 12800) packed frags (2 p-variants x 64 lanes x 100)
//                     [12800 .. 16896) WxL: 32 x 128 f32 (rows 29..31 zeroed)
#define WXL_OFF 12800

typedef __attribute__((ext_vector_type(8))) short bf16x8;
typedef __attribute__((ext_vector_type(4))) float f32x4;
typedef __attribute__((ext_vector_type(2))) unsigned int u32x2;

__device__ __forceinline__ unsigned int f2bf(float f) {
    unsigned u = __float_as_uint(f);
    u += 0x7fff + ((u >> 16) & 1);   // RNE
    return u >> 16;
}
__device__ __forceinline__ unsigned int pk2bf(float a, float b) {
    return f2bf(a) | (f2bf(b) << 16);
}
__device__ __forceinline__ bf16x8 cvt8(f32x4 a, f32x4 b) {
    union { unsigned int u[4]; bf16x8 v; } r;
    asm("v_cvt_pk_bf16_f32 %0, %1, %2" : "=v"(r.u[0]) : "v"(a[0]), "v"(a[1]));
    asm("v_cvt_pk_bf16_f32 %0, %1, %2" : "=v"(r.u[1]) : "v"(a[2]), "v"(a[3]));
    asm("v_cvt_pk_bf16_f32 %0, %1, %2" : "=v"(r.u[2]) : "v"(b[0]), "v"(b[1]));
    asm("v_cvt_pk_bf16_f32 %0, %1, %2" : "=v"(r.u[3]) : "v"(b[2]), "v"(b[3]));
    return r.v;
}

// pack1: blocks 0..28 compute WxL row k (Wx = W1@W2a; row 28 = b2 + b1@W2a, the
// bias row hit by x-frag element k=28 := 1.0; block 28 also zeroes rows 29..31).
// Block 29 packs W2b A-frags (both p-halves); block 30 packs W3 frags + b3
// (p=0 rows only — the epilogue wave).
__global__ void pack1(const float* __restrict__ W1, const float* __restrict__ b1,
                      const float* __restrict__ W2, const float* __restrict__ b2,
                      const float* __restrict__ W3, const float* __restrict__ b3,
                      unsigned int* __restrict__ ws) {
    float* WxL = (float*)(ws + WXL_OFF);
    const int bid = blockIdx.x, tid = threadIdx.x;
    if (bid < 29) {
        const int k = bid, n = tid;   // 128 threads
        float s = 0.f;
        if (k < 28) {
            for (int m = 0; m < 128; ++m) s += W1[k * 128 + m] * W2[m * 128 + n];
        } else {
            s = b2[n];
            for (int m = 0; m < 128; ++m) s += b1[m] * W2[m * 128 + n];
        }
        WxL[k * 128 + n] = s;
        if (k == 28) { WxL[29*128+n] = 0.f; WxL[30*128+n] = 0.f; WxL[31*128+n] = 0.f; }
    } else if (bid == 29) {
        if (tid < 64) {
            const int lr = tid & 15, kh = tid >> 4;
            for (int p = 0; p < 2; ++p) {
                unsigned int* P = ws + (p * 64 + tid) * PACK_DW;
                for (int kk = 0; kk < 4; ++kk)
                    for (int t = 0; t < 4; ++t)
                        for (int jd = 0; jd < 4; ++jd) {
                            const int k = 128 + kk * 32 + kh * 8 + jd * 2;
                            const int n = p * 64 + t * 16 + lr;
                            P[(kk * 4 + t) * 4 + jd] =
                                pk2bf(W2[k * 128 + n], W2[(k + 1) * 128 + n]);
                        }
            }
        }
    } else {
        if (tid < 64) {
            const int lr = tid & 15, kh = tid >> 4;
            unsigned int* P = ws + tid * PACK_DW;   // p=0 rows only
            for (int kk = 0; kk < 4; ++kk)
                for (int jd = 0; jd < 4; ++jd) {
                    const int k = kk * 32 + kh * 8 + jd * 2;
                    float lo = (lr < 10) ? W3[k * 10 + lr] : 0.f;
                    float hi = (lr < 10) ? W3[(k + 1) * 10 + lr] : 0.f;
                    P[80 + kk * 4 + jd] = pk2bf(lo, hi);
                }
            for (int j = 0; j < 4; ++j) {
                const int o = kh * 4 + j;
                P[96 + j] = __float_as_uint((o < 10) ? b3[o] : 0.f);
            }
        }
    }
}

// pack2: Wx A-frags (needs WxL from pack1's blocks 0..28).
__global__ void pack2(unsigned int* __restrict__ ws) {
    const int tid = threadIdx.x;
    if (tid < 64) {
        const float* WxL = (const float*)(ws + WXL_OFF);
        const int lr = tid & 15, kh = tid >> 4;
        for (int p = 0; p < 2; ++p) {
            unsigned int* P = ws + (p * 64 + tid) * PACK_DW;
            for (int t = 0; t < 4; ++t)
                for (int jd = 0; jd < 4; ++jd) {
                    const int k = kh * 8 + jd * 2, n = p * 64 + t * 16 + lr;
                    P[64 + t * 4 + jd] = pk2bf(WxL[k * 128 + n], WxL[(k + 1) * 128 + n]);
                }
        }
    }
}

// Block = 2 waves; wave p owns n-half [64p,64p+64) for TWO batch teams
// (A = rows r0.., B = rows r0+16..). Both teams' chains live IN THE SAME WAVE
// and interleave at issue (guaranteed ILP — not at the scheduler's mercy).
// This is round 7's idea at a 256-reg budget (launch_bounds(128,2)): round 7
// spilled at the 170-reg cap of min-waves=3. Frag-order H (r11) + raw
// lgkmcnt-only barrier (r13) retained.
__global__ __launch_bounds__(128, 2) void rnn_kernel(
    const float* __restrict__ x, const unsigned int* __restrict__ wsPack,
    float* __restrict__ out)
{
    __shared__ __align__(16) unsigned int Hs[2][2][1024];  // [team][buf][frag-order]
    const int tid = threadIdx.x;
    const int p = tid >> 6, lane = tid & 63, lr = lane & 15, kh = lane >> 4;
    const int r0 = blockIdx.x * 32;

    const unsigned int* P = wsPack + (p * 64 + lane) * PACK_DW;
    bf16x8 w2b[4][4], wx[4];
    #pragma unroll
    for (int kk = 0; kk < 4; ++kk)
        #pragma unroll
        for (int t = 0; t < 4; ++t)
            w2b[kk][t] = *(const bf16x8*)(P + (kk * 4 + t) * 4);
    #pragma unroll
    for (int t = 0; t < 4; ++t) wx[t] = *(const bf16x8*)(P + 64 + t * 4);

    // write-address constants per (p, t4, kh): hidden base q0 = p*64+t4*16+kh*4
    //   kkW = p*2 + (t4>>1); khR = (t4*2 + (kh>>1)) & 3; jd = 2*(kh&1)
    unsigned wAddr[4];
    #pragma unroll
    for (int t4 = 0; t4 < 4; ++t4) {
        const int kkW = p * 2 + (t4 >> 1);
        const int khR = (t4 * 2 + (kh >> 1)) & 3;
        const int jd  = (kh & 1) * 2;
        wAddr[t4] = kkW * 256 + khR * 64 + lr * 4 + jd;
    }

    // zero buf0 of both teams (2 x 1024 uints, 128 threads -> 16 each)
    #pragma unroll
    for (int i = 0; i < 8; ++i) {
        Hs[0][0][tid + i * 128] = 0u;
        Hs[1][0][tid + i * 128] = 0u;
    }
    __syncthreads();

    // x B-frag: lane (kh,lr) reads x[row][28t + 8kh + j]; kh==3 upper half is
    // {1.0 (k=28 bias hook), 0,0,0} — Wx rows 29..31 are zero.
    const f32x4 onec = {1.f, 0.f, 0.f, 0.f};
    const float* xrA = x + (size_t)(r0 + lr) * 784 + 8 * kh;
    const float* xrB = xrA + 16 * 784;
    f32x4 qa = *(const f32x4*)xrA;
    f32x4 qc = (kh < 3) ? *(const f32x4*)(xrA + 4) : onec;
    bf16x8 xbA = cvt8(qa, qc);
    qa = *(const f32x4*)xrB;
    qc = (kh < 3) ? *(const f32x4*)(xrB + 4) : onec;
    bf16x8 xbB = cvt8(qa, qc);
    const f32x4 z4 = {0.f, 0.f, 0.f, 0.f};

    int cur = 0;
    for (int t = 0; t < TST; ++t) {
        // issue next-x loads FIRST; they stay in flight across the raw barrier
        f32x4 naA, ncA, naB, ncB;
        const bool pf = (t + 1 < TST);
        if (pf) {
            const float* xp = xrA + (t + 1) * 28;
            naA = *(const f32x4*)xp;
            ncA = (kh < 3) ? *(const f32x4*)(xp + 4) : onec;
            xp = xrB + (t + 1) * 28;
            naB = *(const f32x4*)xp;
            ncB = (kh < 3) ? *(const f32x4*)(xp + 4) : onec;
        }

        // h B-frags for both teams: lane-linear b128 reads (zero conflicts)
        bf16x8 hbvA[4], hbvB[4];
        #pragma unroll
        for (int kk = 0; kk < 4; ++kk) {
            hbvA[kk] = *(const bf16x8*)&Hs[0][cur][kk * 256 + lane * 4];
            hbvB[kk] = *(const bf16x8*)&Hs[1][cur][kk * 256 + lane * 4];
        }

        // interleaved MFMAs: two independent chains per acc slot
        f32x4 accA[4], accB[4];
        #pragma unroll
        for (int t4 = 0; t4 < 4; ++t4) {
            accA[t4] = __builtin_amdgcn_mfma_f32_16x16x32_bf16(wx[t4], xbA, z4, 0, 0, 0);
            accB[t4] = __builtin_amdgcn_mfma_f32_16x16x32_bf16(wx[t4], xbB, z4, 0, 0, 0);
        }
        #pragma unroll
        for (int kk = 0; kk < 4; ++kk)
            #pragma unroll
            for (int t4 = 0; t4 < 4; ++t4) {
                accA[t4] = __builtin_amdgcn_mfma_f32_16x16x32_bf16(w2b[kk][t4], hbvA[kk], accA[t4], 0, 0, 0);
                accB[t4] = __builtin_amdgcn_mfma_f32_16x16x32_bf16(w2b[kk][t4], hbvB[kk], accB[t4], 0, 0, 0);
            }

        // relu + pack + store both teams (b64 each, <=2-way aliased)
        #pragma unroll
        for (int t4 = 0; t4 < 4; ++t4) {
            f32x4 va = accA[t4], vb = accB[t4];
            va[0] = fmaxf(va[0], 0.f); va[1] = fmaxf(va[1], 0.f);
            va[2] = fmaxf(va[2], 0.f); va[3] = fmaxf(va[3], 0.f);
            vb[0] = fmaxf(vb[0], 0.f); vb[1] = fmaxf(vb[1], 0.f);
            vb[2] = fmaxf(vb[2], 0.f); vb[3] = fmaxf(vb[3], 0.f);
            unsigned lo, hi;
            asm("v_cvt_pk_bf16_f32 %0, %1, %2" : "=v"(lo) : "v"(va[0]), "v"(va[1]));
            asm("v_cvt_pk_bf16_f32 %0, %1, %2" : "=v"(hi) : "v"(va[2]), "v"(va[3]));
            u32x2 stA = {lo, hi};
            *(u32x2*)&Hs[0][cur ^ 1][wAddr[t4]] = stA;
            asm("v_cvt_pk_bf16_f32 %0, %1, %2" : "=v"(lo) : "v"(vb[0]), "v"(vb[1]));
            asm("v_cvt_pk_bf16_f32 %0, %1, %2" : "=v"(hi) : "v"(vb[2]), "v"(vb[3]));
            u32x2 stB = {lo, hi};
            *(u32x2*)&Hs[1][cur ^ 1][wAddr[t4]] = stB;
        }
        if (pf) { xbA = cvt8(naA, ncA); xbB = cvt8(naB, ncB); }
        // raw barrier: order LDS (lgkmcnt) but leave global loads in flight
        asm volatile("s_waitcnt lgkmcnt(0)\n\ts_barrier" ::: "memory");
        cur ^= 1;
    }

    // epilogue: p==0 wave computes both teams' out^T = W3^T.h^T + b3
    if (p == 0) {
        bf16x8 w3f[4];
        #pragma unroll
        for (int kk = 0; kk < 4; ++kk) w3f[kk] = *(const bf16x8*)(P + 80 + kk * 4);
        const float* bp = (const float*)(P + 96);
        #pragma unroll
        for (int g = 0; g < 2; ++g) {
            f32x4 accO = {bp[0], bp[1], bp[2], bp[3]};
            #pragma unroll
            for (int kk = 0; kk < 4; ++kk) {
                bf16x8 hb = *(const bf16x8*)&Hs[g][cur][kk * 256 + lane * 4];
                accO = __builtin_amdgcn_mfma_f32_16x16x32_bf16(w3f[kk], hb, accO, 0, 0, 0);
            }
            float* op = out + (size_t)(r0 + g * 16 + lr) * 10 + kh * 4;
            #pragma unroll
            for (int j = 0; j < 4; ++j)
                if (kh * 4 + j < 10) op[j] = accO[j];
        }
    }
}

extern "C" void kernel_launch(void* const* d_in, const int* in_sizes, int n_in,
                              void* d_out, int out_size, void* d_ws, size_t ws_size,
                              hipStream_t stream) {
    const float* x  = (const float*)d_in[0];
    const float* W1 = (const float*)d_in[1];
    const float* b1 = (const float*)d_in[2];
    const float* W2 = (const float*)d_in[3];
    const float* b2 = (const float*)d_in[4];
    const float* W3 = (const float*)d_in[5];
    const float* b3 = (const float*)d_in[6];
    unsigned int* ws = (unsigned int*)d_ws;   // 16896 dwords = 66 KiB

    pack1<<<31, 128, 0, stream>>>(W1, b1, W2, b2, W3, b3, ws);
    pack2<<<1, 64, 0, stream>>>(ws);
    rnn_kernel<<<BTOT / 32, 128, 0, stream>>>(x, ws, (float*)d_out);
}

// Round 17
// 78.620 us; speedup vs baseline: 1.0721x; 1.0721x over previous
//
#include <hip/hip_runtime.h>

#define BTOT 65536
#define TST  28
#define PACK_DW 180
// ws layout (dwords): [0 .. 11520) packed frags (64 lanes x 180)
//                     [11520 .. 15616) WxL: 32 x 128 f32 (rows 29..31 zeroed)
#define WXL_OFF (64 * PACK_DW)

typedef __attribute__((ext_vector_type(8))) short bf16x8;
typedef __attribute__((ext_vector_type(4))) float f32x4;
typedef __attribute__((ext_vector_type(4))) unsigned int u32x4;
typedef __attribute__((ext_vector_type(2))) unsigned int u32x2;

__device__ __forceinline__ unsigned int f2bf(float f) {
    unsigned u = __float_as_uint(f);
    u += 0x7fff + ((u >> 16) & 1);   // RNE
    return u >> 16;
}
__device__ __forceinline__ unsigned int pk2bf(float a, float b) {
    return f2bf(a) | (f2bf(b) << 16);
}
__device__ __forceinline__ bf16x8 cvt8(f32x4 a, f32x4 b) {
    union { unsigned int u[4]; bf16x8 v; } r;
    asm("v_cvt_pk_bf16_f32 %0, %1, %2" : "=v"(r.u[0]) : "v"(a[0]), "v"(a[1]));
    asm("v_cvt_pk_bf16_f32 %0, %1, %2" : "=v"(r.u[1]) : "v"(a[2]), "v"(a[3]));
    asm("v_cvt_pk_bf16_f32 %0, %1, %2" : "=v"(r.u[2]) : "v"(b[0]), "v"(b[1]));
    asm("v_cvt_pk_bf16_f32 %0, %1, %2" : "=v"(r.u[3]) : "v"(b[2]), "v"(b[3]));
    return r.v;
}

// pack1: blocks 0..28 compute WxL row k (Wx = W1@W2a; row 28 = b2 + b1@W2a, hit
// by x-frag element k=28 := 1.0; block 28 zeroes rows 29..31). Block 29 packs
// W2b A-frags (all 8 t8-tiles); block 30 packs W3 frags + b3 D-init.
// Per-lane dword layout: [0..128) w2b(kk,t8) | [128..160) wx(t8)
//                        [160..176) w3(kk)   | [176..180) b3 (f32, D rows)
__global__ void pack1(const float* __restrict__ W1, const float* __restrict__ b1,
                      const float* __restrict__ W2, const float* __restrict__ b2,
                      const float* __restrict__ W3, const float* __restrict__ b3,
                      unsigned int* __restrict__ ws) {
    float* WxL = (float*)(ws + WXL_OFF);
    const int bid = blockIdx.x, tid = threadIdx.x;
    if (bid < 29) {
        const int k = bid, n = tid;   // 128 threads
        float s = 0.f;
        if (k < 28) {
            for (int m = 0; m < 128; ++m) s += W1[k * 128 + m] * W2[m * 128 + n];
        } else {
            s = b2[n];
            for (int m = 0; m < 128; ++m) s += b1[m] * W2[m * 128 + n];
        }
        WxL[k * 128 + n] = s;
        if (k == 28) { WxL[29*128+n] = 0.f; WxL[30*128+n] = 0.f; WxL[31*128+n] = 0.f; }
    } else if (bid == 29) {
        if (tid < 64) {
            const int lr = tid & 15, kh = tid >> 4;
            unsigned int* P = ws + tid * PACK_DW;
            for (int kk = 0; kk < 4; ++kk)
                for (int t8 = 0; t8 < 8; ++t8)
                    for (int jd = 0; jd < 4; ++jd) {
                        const int k = 128 + kk * 32 + kh * 8 + jd * 2;
                        const int n = t8 * 16 + lr;
                        P[(kk * 8 + t8) * 4 + jd] =
                            pk2bf(W2[k * 128 + n], W2[(k + 1) * 128 + n]);
                    }
        }
    } else {
        if (tid < 64) {
            const int lr = tid & 15, kh = tid >> 4;
            unsigned int* P = ws + tid * PACK_DW;
            for (int kk = 0; kk < 4; ++kk)
                for (int jd = 0; jd < 4; ++jd) {
                    const int k = kk * 32 + kh * 8 + jd * 2;
                    float lo = (lr < 10) ? W3[k * 10 + lr] : 0.f;
                    float hi = (lr < 10) ? W3[(k + 1) * 10 + lr] : 0.f;
                    P[160 + kk * 4 + jd] = pk2bf(lo, hi);
                }
            for (int j = 0; j < 4; ++j) {
                const int o = kh * 4 + j;
                P[176 + j] = __float_as_uint((o < 10) ? b3[o] : 0.f);
            }
        }
    }
}

// pack2: Wx A-frags (needs WxL from pack1's blocks 0..28).
__global__ void pack2(unsigned int* __restrict__ ws) {
    const int tid = threadIdx.x;
    if (tid < 64) {
        const float* WxL = (const float*)(ws + WXL_OFF);
        const int lr = tid & 15, kh = tid >> 4;
        unsigned int* P = ws + tid * PACK_DW;
        for (int t8 = 0; t8 < 8; ++t8)
            for (int jd = 0; jd < 4; ++jd) {
                const int k = kh * 8 + jd * 2, n = t8 * 16 + lr;
                P[128 + t8 * 4 + jd] = pk2bf(WxL[k * 128 + n], WxL[(k + 1) * 128 + n]);
            }
    }
}

// Block = ONE wave owning 16 batch rows and ALL 128 n. ZERO barriers: the
// recurrence is wave-private; H round-trips through a 4KB wave-private LDS
// buffer in B-FRAG ORDER (dword idx kk*256 + lane*4 + jd). In-wave DS ops are
// ordered, and the step's writes depend (via the MFMA chain) on its reads, so
// a single buffer is race-free. 8 free-running waves/CU interleave their stall
// phases instead of convoying at block barriers (the r6-r16 plateau).
__global__ __launch_bounds__(64, 2) void rnn_kernel(
    const float* __restrict__ x, const unsigned int* __restrict__ wsPack,
    float* __restrict__ out)
{
    __shared__ __align__(16) unsigned int Hs[1024];   // 4 kk-frags x 256 dwords
    const int lane = threadIdx.x;
    const int lr = lane & 15, kh = lane >> 4;
    const int r0 = blockIdx.x * 16;

    const unsigned int* P = wsPack + lane * PACK_DW;
    bf16x8 w2b[4][8], wx[8];
    #pragma unroll
    for (int kk = 0; kk < 4; ++kk)
        #pragma unroll
        for (int t8 = 0; t8 < 8; ++t8)
            w2b[kk][t8] = *(const bf16x8*)(P + (kk * 8 + t8) * 4);
    #pragma unroll
    for (int t8 = 0; t8 < 8; ++t8) wx[t8] = *(const bf16x8*)(P + 128 + t8 * 4);

    // write addresses (dwords): D-tile t8 row kh*4+j, batch lr ->
    // frag kk=t8>>1, reader-lane row 2*(t8&1)+(kh>>1), dword (kh&1)*2
    unsigned wAddr[8];
    #pragma unroll
    for (int t8 = 0; t8 < 8; ++t8)
        wAddr[t8] = (t8 >> 1) * 256 + (2 * (t8 & 1) + (kh >> 1)) * 64
                  + lr * 4 + (kh & 1) * 2;

    // h0 = 0 (wave-private; in-wave ordering suffices, no barrier)
    #pragma unroll
    for (int i = 0; i < 4; ++i)
        ((u32x4*)Hs)[lane + i * 64] = (u32x4){0u, 0u, 0u, 0u};

    // x B-frag: lane (kh,lr) covers k = 8kh + j of x[r0+lr][28t + k];
    // kh==3 upper half = {1.0 (k=28 bias hook), 0, 0, 0} — Wx rows 29..31 zero.
    const f32x4 onec = {1.f, 0.f, 0.f, 0.f};
    const float* xr = x + (size_t)(r0 + lr) * 784 + 8 * kh;
    f32x4 xa = *(const f32x4*)xr;
    f32x4 xc = (kh < 3) ? *(const f32x4*)(xr + 4) : onec;
    bf16x8 xb = cvt8(xa, xc);
    const f32x4 z4 = {0.f, 0.f, 0.f, 0.f};

    for (int t = 0; t < TST; ++t) {
        // issue next-x load at the top; ~full step of MFMAs hides its latency
        f32x4 na, nc;
        const bool pf = (t + 1 < TST);
        if (pf) {
            const float* xp = xr + (t + 1) * 28;
            na = *(const f32x4*)xp;
            nc = (kh < 3) ? *(const f32x4*)(xp + 4) : onec;
        }

        // h B-frags: 4 lane-linear b128 reads (conflict-free); x-MFMAs below
        // cover their latency
        bf16x8 hbv[4];
        #pragma unroll
        for (int kk = 0; kk < 4; ++kk)
            hbv[kk] = *(const bf16x8*)&Hs[kk * 256 + lane * 4];

        f32x4 acc[8];
        #pragma unroll
        for (int t8 = 0; t8 < 8; ++t8)
            acc[t8] = __builtin_amdgcn_mfma_f32_16x16x32_bf16(wx[t8], xb, z4, 0, 0, 0);
        #pragma unroll
        for (int kk = 0; kk < 4; ++kk)
            #pragma unroll
            for (int t8 = 0; t8 < 8; ++t8)
                acc[t8] = __builtin_amdgcn_mfma_f32_16x16x32_bf16(w2b[kk][t8], hbv[kk], acc[t8], 0, 0, 0);

        // relu + pack -> one b64 store per tile into frag-order slots
        #pragma unroll
        for (int t8 = 0; t8 < 8; ++t8) {
            f32x4 v = acc[t8];
            v[0] = fmaxf(v[0], 0.f); v[1] = fmaxf(v[1], 0.f);
            v[2] = fmaxf(v[2], 0.f); v[3] = fmaxf(v[3], 0.f);
            unsigned lo, hi;
            asm("v_cvt_pk_bf16_f32 %0, %1, %2" : "=v"(lo) : "v"(v[0]), "v"(v[1]));
            asm("v_cvt_pk_bf16_f32 %0, %1, %2" : "=v"(hi) : "v"(v[2]), "v"(v[3]));
            u32x2 st = {lo, hi};
            *(u32x2*)&Hs[wAddr[t8]] = st;
        }
        if (pf) xb = cvt8(na, nc);
    }

    // epilogue: out^T = W3^T . h^T + b3 (wave-private, no sync needed)
    bf16x8 w3f[4];
    #pragma unroll
    for (int kk = 0; kk < 4; ++kk) w3f[kk] = *(const bf16x8*)(P + 160 + kk * 4);
    const float* bp = (const float*)(P + 176);
    f32x4 accO = {bp[0], bp[1], bp[2], bp[3]};
    #pragma unroll
    for (int kk = 0; kk < 4; ++kk) {
        bf16x8 hb = *(const bf16x8*)&Hs[kk * 256 + lane * 4];
        accO = __builtin_amdgcn_mfma_f32_16x16x32_bf16(w3f[kk], hb, accO, 0, 0, 0);
    }
    float* op = out + (size_t)(r0 + lr) * 10 + kh * 4;
    #pragma unroll
    for (int j = 0; j < 4; ++j)
        if (kh * 4 + j < 10) op[j] = accO[j];
}

extern "C" void kernel_launch(void* const* d_in, const int* in_sizes, int n_in,
                              void* d_out, int out_size, void* d_ws, size_t ws_size,
                              hipStream_t stream) {
    const float* x  = (const float*)d_in[0];
    const float* W1 = (const float*)d_in[1];
    const float* b1 = (const float*)d_in[2];
    const float* W2 = (const float*)d_in[3];
    const float* b2 = (const float*)d_in[4];
    const float* W3 = (const float*)d_in[5];
    const float* b3 = (const float*)d_in[6];
    unsigned int* ws = (unsigned int*)d_ws;   // 15616 dwords = 61 KiB

    pack1<<<31, 128, 0, stream>>>(W1, b1, W2, b2, W3, b3, ws);
    pack2<<<1, 64, 0, stream>>>(ws);
    rnn_kernel<<<BTOT / 16, 64, 0, stream>>>(x, ws, (float*)d_out);
}

// Round 18
// 76.899 us; speedup vs baseline: 1.0961x; 1.0224x over previous
//
#include <hip/hip_runtime.h>

#define BTOT 65536
#define TST  28
#define PACK_DW 180
// ws layout (dwords): [0 .. 11520) packed frags (64 lanes x 180)
//                     [11520 .. 15616) WxL: 32 x 128 f32 (rows 29..31 zeroed)
#define WXL_OFF (64 * PACK_DW)

typedef __attribute__((ext_vector_type(8))) short bf16x8;
typedef __attribute__((ext_vector_type(4))) float f32x4;
typedef __attribute__((ext_vector_type(4))) unsigned int u32x4;
typedef __attribute__((ext_vector_type(2))) unsigned int u32x2;

__device__ __forceinline__ unsigned int f2bf(float f) {
    unsigned u = __float_as_uint(f);
    u += 0x7fff + ((u >> 16) & 1);   // RNE
    return u >> 16;
}
__device__ __forceinline__ unsigned int pk2bf(float a, float b) {
    return f2bf(a) | (f2bf(b) << 16);
}
__device__ __forceinline__ bf16x8 cvt8(f32x4 a, f32x4 b) {
    union { unsigned int u[4]; bf16x8 v; } r;
    asm("v_cvt_pk_bf16_f32 %0, %1, %2" : "=v"(r.u[0]) : "v"(a[0]), "v"(a[1]));
    asm("v_cvt_pk_bf16_f32 %0, %1, %2" : "=v"(r.u[1]) : "v"(a[2]), "v"(a[3]));
    asm("v_cvt_pk_bf16_f32 %0, %1, %2" : "=v"(r.u[2]) : "v"(b[0]), "v"(b[1]));
    asm("v_cvt_pk_bf16_f32 %0, %1, %2" : "=v"(r.u[3]) : "v"(b[2]), "v"(b[3]));
    return r.v;
}

// pack1: blocks 0..28 compute WxL row k (Wx = W1@W2a; row 28 = b2 + b1@W2a, hit
// by x-frag element k=28 := 1.0; block 28 zeroes rows 29..31). Block 29 packs
// W2b A-frags (all 8 t8-tiles); block 30 packs W3 frags + b3 D-init.
// Per-lane dword layout: [0..128) w2b(kk,t8) | [128..160) wx(t8)
//                        [160..176) w3(kk)   | [176..180) b3 (f32, D rows)
__global__ void pack1(const float* __restrict__ W1, const float* __restrict__ b1,
                      const float* __restrict__ W2, const float* __restrict__ b2,
                      const float* __restrict__ W3, const float* __restrict__ b3,
                      unsigned int* __restrict__ ws) {
    float* WxL = (float*)(ws + WXL_OFF);
    const int bid = blockIdx.x, tid = threadIdx.x;
    if (bid < 29) {
        const int k = bid, n = tid;   // 128 threads
        float s = 0.f;
        if (k < 28) {
            for (int m = 0; m < 128; ++m) s += W1[k * 128 + m] * W2[m * 128 + n];
        } else {
            s = b2[n];
            for (int m = 0; m < 128; ++m) s += b1[m] * W2[m * 128 + n];
        }
        WxL[k * 128 + n] = s;
        if (k == 28) { WxL[29*128+n] = 0.f; WxL[30*128+n] = 0.f; WxL[31*128+n] = 0.f; }
    } else if (bid == 29) {
        if (tid < 64) {
            const int lr = tid & 15, kh = tid >> 4;
            unsigned int* P = ws + tid * PACK_DW;
            for (int kk = 0; kk < 4; ++kk)
                for (int t8 = 0; t8 < 8; ++t8)
                    for (int jd = 0; jd < 4; ++jd) {
                        const int k = 128 + kk * 32 + kh * 8 + jd * 2;
                        const int n = t8 * 16 + lr;
                        P[(kk * 8 + t8) * 4 + jd] =
                            pk2bf(W2[k * 128 + n], W2[(k + 1) * 128 + n]);
                    }
        }
    } else {
        if (tid < 64) {
            const int lr = tid & 15, kh = tid >> 4;
            unsigned int* P = ws + tid * PACK_DW;
            for (int kk = 0; kk < 4; ++kk)
                for (int jd = 0; jd < 4; ++jd) {
                    const int k = kk * 32 + kh * 8 + jd * 2;
                    float lo = (lr < 10) ? W3[k * 10 + lr] : 0.f;
                    float hi = (lr < 10) ? W3[(k + 1) * 10 + lr] : 0.f;
                    P[160 + kk * 4 + jd] = pk2bf(lo, hi);
                }
            for (int j = 0; j < 4; ++j) {
                const int o = kh * 4 + j;
                P[176 + j] = __float_as_uint((o < 10) ? b3[o] : 0.f);
            }
        }
    }
}

// pack2: Wx A-frags (needs WxL from pack1's blocks 0..28).
__global__ void pack2(unsigned int* __restrict__ ws) {
    const int tid = threadIdx.x;
    if (tid < 64) {
        const float* WxL = (const float*)(ws + WXL_OFF);
        const int lr = tid & 15, kh = tid >> 4;
        unsigned int* P = ws + tid * PACK_DW;
        for (int t8 = 0; t8 < 8; ++t8)
            for (int jd = 0; jd < 4; ++jd) {
                const int k = kh * 8 + jd * 2, n = t8 * 16 + lr;
                P[128 + t8 * 4 + jd] = pk2bf(WxL[k * 128 + n], WxL[(k + 1) * 128 + n]);
            }
    }
}

// r17 base (78.6us): block = ONE wave, 16 batch rows, all 128 n, zero barriers,
// wave-private frag-order H in LDS. This round adds: (1) unroll-2 so step t+1's
// x-MFMAs slide into step t's cvt/store tail; (2) s_setprio around the MFMA
// cluster (T5 — free-running 1-wave blocks is the attn regime where it paid);
// (3) half-step s_sleep stagger on odd blocks to decorrelate co-resident waves'
// stall phases (anti-convoy).
__global__ __launch_bounds__(64, 2) void rnn_kernel(
    const float* __restrict__ x, const unsigned int* __restrict__ wsPack,
    float* __restrict__ out)
{
    __shared__ __align__(16) unsigned int Hs[1024];   // 4 kk-frags x 256 dwords
    const int lane = threadIdx.x;
    const int lr = lane & 15, kh = lane >> 4;
    const int r0 = blockIdx.x * 16;

    const unsigned int* P = wsPack + lane * PACK_DW;
    bf16x8 w2b[4][8], wx[8];
    #pragma unroll
    for (int kk = 0; kk < 4; ++kk)
        #pragma unroll
        for (int t8 = 0; t8 < 8; ++t8)
            w2b[kk][t8] = *(const bf16x8*)(P + (kk * 8 + t8) * 4);
    #pragma unroll
    for (int t8 = 0; t8 < 8; ++t8) wx[t8] = *(const bf16x8*)(P + 128 + t8 * 4);

    // write addresses (dwords): D-tile t8 row kh*4+j, batch lr ->
    // frag kk=t8>>1, reader-lane row 2*(t8&1)+(kh>>1), dword (kh&1)*2
    unsigned wAddr[8];
    #pragma unroll
    for (int t8 = 0; t8 < 8; ++t8)
        wAddr[t8] = (t8 >> 1) * 256 + (2 * (t8 & 1) + (kh >> 1)) * 64
                  + lr * 4 + (kh & 1) * 2;

    // h0 = 0 (wave-private; in-wave ordering suffices, no barrier)
    #pragma unroll
    for (int i = 0; i < 4; ++i)
        ((u32x4*)Hs)[lane + i * 64] = (u32x4){0u, 0u, 0u, 0u};

    // x B-frag: lane (kh,lr) covers k = 8kh + j of x[r0+lr][28t + k];
    // kh==3 upper half = {1.0 (k=28 bias hook), 0, 0, 0} — Wx rows 29..31 zero.
    const f32x4 onec = {1.f, 0.f, 0.f, 0.f};
    const float* xr = x + (size_t)(r0 + lr) * 784 + 8 * kh;
    f32x4 xa = *(const f32x4*)xr;
    f32x4 xc = (kh < 3) ? *(const f32x4*)(xr + 4) : onec;
    bf16x8 xb = cvt8(xa, xc);
    const f32x4 z4 = {0.f, 0.f, 0.f, 0.f};

    // anti-convoy stagger: odd blocks phase-shift ~half a step
    if (blockIdx.x & 1) __builtin_amdgcn_s_sleep(8);

    #pragma unroll 2
    for (int t = 0; t < TST; ++t) {
        // issue next-x load at the top; a full step of MFMAs hides its latency
        f32x4 na, nc;
        const bool pf = (t + 1 < TST);
        if (pf) {
            const float* xp = xr + (t + 1) * 28;
            na = *(const f32x4*)xp;
            nc = (kh < 3) ? *(const f32x4*)(xp + 4) : onec;
        }

        // h B-frags: 4 lane-linear b128 reads (conflict-free)
        bf16x8 hbv[4];
        #pragma unroll
        for (int kk = 0; kk < 4; ++kk)
            hbv[kk] = *(const bf16x8*)&Hs[kk * 256 + lane * 4];

        __builtin_amdgcn_s_setprio(1);
        f32x4 acc[8];
        #pragma unroll
        for (int t8 = 0; t8 < 8; ++t8)
            acc[t8] = __builtin_amdgcn_mfma_f32_16x16x32_bf16(wx[t8], xb, z4, 0, 0, 0);
        #pragma unroll
        for (int kk = 0; kk < 4; ++kk)
            #pragma unroll
            for (int t8 = 0; t8 < 8; ++t8)
                acc[t8] = __builtin_amdgcn_mfma_f32_16x16x32_bf16(w2b[kk][t8], hbv[kk], acc[t8], 0, 0, 0);
        __builtin_amdgcn_s_setprio(0);

        // consume next x early (independent of the stores below)
        if (pf) xb = cvt8(na, nc);

        // relu + pack -> one b64 store per tile into frag-order slots
        #pragma unroll
        for (int t8 = 0; t8 < 8; ++t8) {
            f32x4 v = acc[t8];
            v[0] = fmaxf(v[0], 0.f); v[1] = fmaxf(v[1], 0.f);
            v[2] = fmaxf(v[2], 0.f); v[3] = fmaxf(v[3], 0.f);
            unsigned lo, hi;
            asm("v_cvt_pk_bf16_f32 %0, %1, %2" : "=v"(lo) : "v"(v[0]), "v"(v[1]));
            asm("v_cvt_pk_bf16_f32 %0, %1, %2" : "=v"(hi) : "v"(v[2]), "v"(v[3]));
            u32x2 st = {lo, hi};
            *(u32x2*)&Hs[wAddr[t8]] = st;
        }
    }

    // epilogue: out^T = W3^T . h^T + b3 (wave-private, no sync needed)
    bf16x8 w3f[4];
    #pragma unroll
    for (int kk = 0; kk < 4; ++kk) w3f[kk] = *(const bf16x8*)(P + 160 + kk * 4);
    const float* bp = (const float*)(P + 176);
    f32x4 accO = {bp[0], bp[1], bp[2], bp[3]};
    #pragma unroll
    for (int kk = 0; kk < 4; ++kk) {
        bf16x8 hb = *(const bf16x8*)&Hs[kk * 256 + lane * 4];
        accO = __builtin_amdgcn_mfma_f32_16x16x32_bf16(w3f[kk], hb, accO, 0, 0, 0);
    }
    float* op = out + (size_t)(r0 + lr) * 10 + kh * 4;
    #pragma unroll
    for (int j = 0; j < 4; ++j)
        if (kh * 4 + j < 10) op[j] = accO[j];
}

extern "C" void kernel_launch(void* const* d_in, const int* in_sizes, int n_in,
                              void* d_out, int out_size, void* d_ws, size_t ws_size,
                              hipStream_t stream) {
    const float* x  = (const float*)d_in[0];
    const float* W1 = (const float*)d_in[1];
    const float* b1 = (const float*)d_in[2];
    const float* W2 = (const float*)d_in[3];
    const float* b2 = (const float*)d_in[4];
    const float* W3 = (const float*)d_in[5];
    const float* b3 = (const float*)d_in[6];
    unsigned int* ws = (unsigned int*)d_ws;   // 15616 dwords = 61 KiB

    pack1<<<31, 128, 0, stream>>>(W1, b1, W2, b2, W3, b3, ws);
    pack2<<<1, 64, 0, stream>>>(ws);
    rnn_kernel<<<BTOT / 16, 64, 0, stream>>>(x, ws, (float*)d_out);
}